// Round 6
// baseline (1518.471 us; speedup 1.0000x reference)
//
#include <hip/hip_runtime.h>
#include <hip/hip_bf16.h>

typedef __bf16 bf16x8 __attribute__((ext_vector_type(8)));
typedef float f32x4 __attribute__((ext_vector_type(4)));
typedef unsigned long long u64;

#define EPSV 1e-5f

__device__ __forceinline__ float bf2f(unsigned short u){
  unsigned int x = ((unsigned int)u) << 16;
  return __builtin_bit_cast(float, x);
}
__device__ __forceinline__ unsigned short f2bf(float f){
  __bf16 b = (__bf16)f;
  return __builtin_bit_cast(unsigned short, b);
}
__device__ __forceinline__ float gelu_exact(float x){
  return 0.5f * x * (1.0f + erff(x * 0.7071067811865476f));
}
__device__ __forceinline__ void gload_lds16(const void* g, void* l){
  __builtin_amdgcn_global_load_lds((const __attribute__((address_space(1))) unsigned int*)g,
                                   (__attribute__((address_space(3))) unsigned int*)l, 16, 0, 0);
}

// ---------------------------------------------------------------------------
// 256x256 (BK=64) 8-wave 4-phase bf16 MFMA GEMM: C = A[M,K] * Bt[N,K]^T (+bias)
// MODE 0: bias+GELU->bf16, dual output (col<4096 -> C0/bias0, else C1/bias1)
// MODE 1: bias->bf16 single
// MODE 3: bias->bf16 pure V-transpose (slab path)
// MODE 4: dual: col<4096 -> K normal (C0); col>=4096 -> V transposed (C1)
// ds_read->MFMA waits: COMPILER-INSERTED fine-grained lgkmcnt (plain loads,
// SSA-tracked). No manual lgkmcnt(0): it serialized each phase on all 12 reads.
// sched_barrier(0) after the pre-MFMA s_barrier pins cluster order only.
// Staging safety: vmcnt(6) gate once per K-tile (counted, never 0 mid-loop);
// every stage targets a region whose readers passed the prior phase barrier.
// LDS XOR swizzle (involution): slot ^= (row>>1)&7, applied on the staging
// *global source* slot and on ds_read (both-sides, G21). Bank-conflict-free.
// ---------------------------------------------------------------------------
template<int MODE>
__global__ __launch_bounds__(512, 2)
void gemm256(const unsigned short* __restrict__ A, const unsigned short* __restrict__ B,
             const float* __restrict__ bias0, const float* __restrict__ bias1,
             void* __restrict__ C0v, void* __restrict__ C1v,
             int Kd, int lda, int ldb, int ldc)
{
  __shared__ char smem[131072];  // A: [2 dbuf][2 half][128][64]b16 @0; B same @65536
  const int t = threadIdx.x;
  const int w = t >> 6, l = t & 63;
  const int wm = w >> 2, wn = w & 3;        // wave grid 2(M) x 4(N)
  const int lr = l & 15, lg = l >> 4;
  // XCD-aware bijective block swizzle (launch shapes keep nwg%8==0)
  const int nbx = gridDim.x;
  const int nwg = nbx * gridDim.y;
  int bid = blockIdx.y*nbx + blockIdx.x;
  if ((nwg & 7) == 0) bid = (bid & 7)*(nwg >> 3) + (bid >> 3);
  const int bm0 = (bid / nbx) * 256, bn0 = (bid % nbx) * 256;
  const int nk = Kd >> 6;

  const int srow = t >> 3;                   // staging row-within-quarter 0..63
  const int sslot = t & 7;                   // staging 16B slot

  f32x4 acc[8][4];
  #pragma unroll
  for (int i=0;i<8;++i){
    #pragma unroll
    for (int j=0;j<4;++j){ f32x4 zz = {0.f,0.f,0.f,0.f}; acc[i][j] = zz; }
  }
  bf16x8 a0[4][2], a1[4][2], b0[2][2], b1[2][2];

  auto stage = [&](int kt, int mat, int hf, int q){
    if (kt >= nk) return;
    const int r_h = q*64 + srow;
    const int s_ = sslot ^ ((r_h >> 1) & 7);
    const unsigned short* gp = (mat ? B + (size_t)(bn0 + hf*128 + r_h)*ldb
                                    : A + (size_t)(bm0 + hf*128 + r_h)*lda)
                               + (kt << 6) + s_*8;
    char* lp = smem + mat*65536 + (kt&1)*32768 + hf*16384 + q*8192 + t*16;
    gload_lds16((const void*)gp, (void*)lp);
  };
  auto rdA = [&](int d, int fm, int kk)->bf16x8{
    const int r = fm*16 + lr;
    const int s_ = (kk*4 + lg) ^ ((r >> 1) & 7);
    return *(const bf16x8*)(smem + d*32768 + wm*16384 + r*128 + s_*16);
  };
  auto rdB = [&](int d, int fn, int kk)->bf16x8{
    const int r = (wn&1)*64 + fn*16 + lr;
    const int s_ = (kk*4 + lg) ^ ((r >> 1) & 7);
    return *(const bf16x8*)(smem + 65536 + d*32768 + (wn>>1)*16384 + r*128 + s_*16);
  };

  auto ktile = [&](int kt, int d){
    // ---- phase 1 ----
    #pragma unroll
    for (int fm=0; fm<4; ++fm){ a0[fm][0] = rdA(d, fm, 0); a0[fm][1] = rdA(d, fm, 1); }
    #pragma unroll
    for (int fn=0; fn<2; ++fn){ b0[fn][0] = rdB(d, fn, 0); b0[fn][1] = rdB(d, fn, 1); }
    stage(kt+1, 0, 0, 1); stage(kt+1, 0, 1, 1);
    __builtin_amdgcn_s_barrier();
    __builtin_amdgcn_sched_barrier(0);
    __builtin_amdgcn_s_setprio(1);
    #pragma unroll
    for (int fm=0; fm<4; ++fm)
      #pragma unroll
      for (int fn=0; fn<2; ++fn)
        #pragma unroll
        for (int kk=0; kk<2; ++kk)
          acc[fm][fn] = __builtin_amdgcn_mfma_f32_16x16x32_bf16(a0[fm][kk], b0[fn][kk], acc[fm][fn], 0,0,0);
    __builtin_amdgcn_s_setprio(0);
    __builtin_amdgcn_s_barrier();
    // ---- phase 2 ----
    #pragma unroll
    for (int fn=0; fn<2; ++fn){ b1[fn][0] = rdB(d, fn+2, 0); b1[fn][1] = rdB(d, fn+2, 1); }
    stage(kt+2, 0, 0, 0); stage(kt+2, 0, 1, 0);
    __builtin_amdgcn_s_barrier();
    __builtin_amdgcn_sched_barrier(0);
    __builtin_amdgcn_s_setprio(1);
    #pragma unroll
    for (int fm=0; fm<4; ++fm)
      #pragma unroll
      for (int fn=0; fn<2; ++fn)
        #pragma unroll
        for (int kk=0; kk<2; ++kk)
          acc[fm][fn+2] = __builtin_amdgcn_mfma_f32_16x16x32_bf16(a0[fm][kk], b1[fn][kk], acc[fm][fn+2], 0,0,0);
    __builtin_amdgcn_s_setprio(0);
    __builtin_amdgcn_s_barrier();
    // ---- phase 3 ----
    #pragma unroll
    for (int fm=0; fm<4; ++fm){ a1[fm][0] = rdA(d, fm+4, 0); a1[fm][1] = rdA(d, fm+4, 1); }
    stage(kt+2, 1, 0, 0); stage(kt+2, 1, 1, 0);
    __builtin_amdgcn_s_barrier();
    __builtin_amdgcn_sched_barrier(0);
    __builtin_amdgcn_s_setprio(1);
    #pragma unroll
    for (int fm=0; fm<4; ++fm)
      #pragma unroll
      for (int fn=0; fn<2; ++fn)
        #pragma unroll
        for (int kk=0; kk<2; ++kk)
          acc[fm+4][fn+2] = __builtin_amdgcn_mfma_f32_16x16x32_bf16(a1[fm][kk], b1[fn][kk], acc[fm+4][fn+2], 0,0,0);
    __builtin_amdgcn_s_setprio(0);
    __builtin_amdgcn_s_barrier();
    // ---- phase 4 ---- (no ds_reads: reuses a1 + b0 from registers)
    stage(kt+2, 1, 0, 1); stage(kt+2, 1, 1, 1);
    __builtin_amdgcn_s_setprio(1);
    #pragma unroll
    for (int fm=0; fm<4; ++fm)
      #pragma unroll
      for (int fn=0; fn<2; ++fn)
        #pragma unroll
        for (int kk=0; kk<2; ++kk)
          acc[fm+4][fn] = __builtin_amdgcn_mfma_f32_16x16x32_bf16(a1[fm][kk], b0[fn][kk], acc[fm+4][fn], 0,0,0);
    __builtin_amdgcn_s_setprio(0);
    if (kt + 2 < nk) { asm volatile("s_waitcnt vmcnt(6)" ::: "memory"); }
    else             { asm volatile("s_waitcnt vmcnt(0)" ::: "memory"); }
    __builtin_amdgcn_s_barrier();
  };

  // prologue: tile0 fully (8 quarters), tile1 minus A-q1 (6 quarters)
  stage(0,0,0,0); stage(0,0,1,0); stage(0,0,0,1); stage(0,0,1,1);
  stage(0,1,0,0); stage(0,1,1,0); stage(0,1,0,1); stage(0,1,1,1);
  stage(1,0,0,0); stage(1,0,1,0);
  stage(1,1,0,0); stage(1,1,1,0); stage(1,1,0,1); stage(1,1,1,1);
  asm volatile("s_waitcnt vmcnt(6)" ::: "memory");
  __builtin_amdgcn_s_barrier();

  for (int kt = 0; kt < nk; kt += 2){ ktile(kt, 0); ktile(kt+1, 1); }

  // epilogue
  #pragma unroll
  for (int fm=0; fm<8; ++fm){
    #pragma unroll
    for (int fn=0; fn<4; ++fn){
      const int row0 = bm0 + wm*128 + fm*16 + lg*4;
      const int col  = bn0 + wn*64 + fn*16 + lr;
      f32x4 v = acc[fm][fn];
      if constexpr (MODE == 3){
        unsigned short* C = (unsigned short*)C0v;
        const float bb = bias0[col];
        u64 pack = 0;
        #pragma unroll
        for (int j=0;j<4;++j) pack |= (u64)f2bf(v[j] + bb) << (16*j);
        *(u64*)(C + (size_t)col*256 + (size_t)(row0>>8)*1048576 + (row0&255)) = pack;
      } else if constexpr (MODE == 4){
        if (col < 4096){
          unsigned short* C = (unsigned short*)C0v;
          const float bb = bias0[col];
          #pragma unroll
          for (int j=0;j<4;++j) C[(size_t)(row0+j)*ldc + col] = f2bf(v[j] + bb);
        } else {
          const int c2 = col - 4096;
          unsigned short* C = (unsigned short*)C1v;
          const float bb = bias1[c2];
          u64 pack = 0;
          #pragma unroll
          for (int j=0;j<4;++j) pack |= (u64)f2bf(v[j] + bb) << (16*j);
          *(u64*)(C + (size_t)c2*256 + (size_t)(row0>>8)*1048576 + (row0&255)) = pack;
        }
      } else {
        const bool hi = (MODE == 0) && (col >= 4096);
        unsigned short* C = (unsigned short*)(hi ? C1v : C0v);
        const int c2 = hi ? (col - 4096) : col;
        const float bb = hi ? bias1[c2] : bias0[c2];
        #pragma unroll
        for (int j=0;j<4;++j){
          float x = v[j] + bb;
          if constexpr (MODE==0) x = gelu_exact(x);
          C[(size_t)(row0+j)*ldc + c2] = f2bf(x);
        }
      }
    }
  }
}

// ---------------------------------------------------------------------------
// 128x128 (BK=32) bf16 MFMA GEMM (small attention GEMMs). MODE 2: *scale->fp32.
// ---------------------------------------------------------------------------
template<int MODE>
__global__ __launch_bounds__(256)
void gemm_bt(const unsigned short* __restrict__ A, const unsigned short* __restrict__ B,
             const float* __restrict__ bias, void* __restrict__ Cv,
             int Kd, int lda, int ldb, int ldc,
             long sA2, long sA1, long sB2, long sB1, long sC2, long sC1,
             float scale)
{
  __shared__ unsigned short lds[2][2][4096];
  const int t = threadIdx.x;
  const int w = t >> 6, l = t & 63;
  const int z = blockIdx.z;
  A += (size_t)(z>>2)*sA2 + (size_t)(z&3)*sA1;
  B += (size_t)(z>>2)*sB2 + (size_t)(z&3)*sB1;
  const int bm0 = blockIdx.y * 128, bn0 = blockIdx.x * 128;
  const int nk = Kd >> 5;

  const int sr = l >> 2;
  const int ss = l & 3;

  f32x4 acc[4][4];
  #pragma unroll
  for (int i=0;i<4;++i){
    #pragma unroll
    for (int j=0;j<4;++j){ f32x4 zz = {0.f,0.f,0.f,0.f}; acc[i][j] = zz; }
  }

  const int wm = w >> 1, wn = w & 1;
  const int lr = l & 15, lg = l >> 4;

  auto stage = [&](int kt, int bb){
    const int k0 = kt << 5;
    #pragma unroll
    for (int i=0;i<2;++i){
      const int r  = w*32 + i*16 + sr;
      const int sa = ss ^ ((r>>1)&3);
      const unsigned short* ga = A + (size_t)(bm0 + r)*lda + (k0 + sa*8);
      gload_lds16((const void*)ga, (void*)((char*)&lds[bb][0][0] + w*2048 + i*1024));
      const unsigned short* gb = B + (size_t)(bn0 + r)*ldb + (k0 + sa*8);
      gload_lds16((const void*)gb, (void*)((char*)&lds[bb][1][0] + w*2048 + i*1024));
    }
  };

  int buf = 0;
  stage(0, 0);
  for (int kt=0; kt<nk; ++kt){
    __syncthreads();
    if (kt+1 < nk) stage(kt+1, buf^1);
    bf16x8 av[4], bv[4];
    #pragma unroll
    for (int fm=0; fm<4; ++fm){
      const int row = wm*64 + fm*16 + lr;
      const int sl  = lg ^ ((row>>1)&3);
      av[fm] = *(const bf16x8*)((const char*)&lds[buf][0][0] + row*64 + sl*16);
    }
    #pragma unroll
    for (int fn=0; fn<4; ++fn){
      const int col = wn*64 + fn*16 + lr;
      const int sl  = lg ^ ((col>>1)&3);
      bv[fn] = *(const bf16x8*)((const char*)&lds[buf][1][0] + col*64 + sl*16);
    }
    #pragma unroll
    for (int fm=0; fm<4; ++fm){
      #pragma unroll
      for (int fn=0; fn<4; ++fn)
        acc[fm][fn] = __builtin_amdgcn_mfma_f32_16x16x32_bf16(av[fm], bv[fn], acc[fm][fn], 0,0,0);
    }
    buf ^= 1;
  }

  const size_t coff = (size_t)(z>>2)*sC2 + (size_t)(z&3)*sC1;
  #pragma unroll
  for (int fm=0; fm<4; ++fm){
    #pragma unroll
    for (int fn=0; fn<4; ++fn){
      const int row0 = bm0 + wm*64 + fm*16 + lg*4;
      const int col  = bn0 + wn*64 + fn*16 + lr;
      f32x4 v = acc[fm][fn];
      if constexpr (MODE == 2){
        float* C = (float*)Cv + coff;
        #pragma unroll
        for (int j=0;j<4;++j) C[(size_t)(row0+j)*ldc + col] = v[j]*scale;
      }
    }
  }
}

// ---------------------------------------------------------------------------
__global__ __launch_bounds__(256)
void k_convh(const float* __restrict__ in, unsigned short* __restrict__ out){
  const size_t id = (size_t)blockIdx.x*256 + threadIdx.x;
  float4 v = ((const float4*)in)[id];
  u64 pack = (u64)f2bf(v.x) | ((u64)f2bf(v.y)<<16) | ((u64)f2bf(v.z)<<32) | ((u64)f2bf(v.w)<<48);
  *(u64*)(out + id*4) = pack;
}

__global__ __launch_bounds__(256)
void k_tconv(const float* __restrict__ W, unsigned short* __restrict__ Wt, int Kd, int N){
  __shared__ float lt[64][65];
  const int t = threadIdx.x;
  const int n0 = blockIdx.x*64, k0 = blockIdx.y*64;
  #pragma unroll
  for (int i=0;i<16;++i){
    int lin = i*256 + t; int r = lin>>6, c = lin&63;
    lt[r][c] = W[(size_t)(k0+r)*N + n0 + c];
  }
  __syncthreads();
  #pragma unroll
  for (int i=0;i<16;++i){
    int lin = i*256 + t; int n = lin>>6, k = lin&63;
    Wt[(size_t)(n0+n)*Kd + k0 + k] = f2bf(lt[k][n]);
  }
}

__global__ __launch_bounds__(256)
void k_softmax(const float* __restrict__ S, unsigned short* __restrict__ P){
  const int t = threadIdx.x, w = t>>6, l = t&63;
  const size_t row = (size_t)blockIdx.x*4 + w;
  float4 v = *(const float4*)(S + row*256 + l*4);
  float m = fmaxf(fmaxf(v.x,v.y), fmaxf(v.z,v.w));
  #pragma unroll
  for (int off=32; off; off>>=1) m = fmaxf(m, __shfl_xor(m, off));
  float e0 = expf(v.x-m), e1 = expf(v.y-m), e2 = expf(v.z-m), e3 = expf(v.w-m);
  float s = e0+e1+e2+e3;
  #pragma unroll
  for (int off=32; off; off>>=1) s += __shfl_xor(s, off);
  const float inv = 1.0f/s;
  u64 pack = (u64)f2bf(e0*inv) | ((u64)f2bf(e1*inv)<<16) | ((u64)f2bf(e2*inv)<<32) | ((u64)f2bf(e3*inv)<<48);
  *(u64*)(P + row*256 + l*4) = pack;
}

__device__ __forceinline__ void blkred2(float& a, float& b, float* sred, int t){
  #pragma unroll
  for (int off=32; off; off>>=1){ a += __shfl_xor(a, off); b += __shfl_xor(b, off); }
  __syncthreads();
  if ((t&63)==0){ sred[(t>>6)*2] = a; sred[(t>>6)*2+1] = b; }
  __syncthreads();
  a = sred[0]+sred[2]+sred[4]+sred[6];
  b = sred[1]+sred[3]+sred[5]+sred[7];
}

__global__ __launch_bounds__(256)
void k_stats(const float* __restrict__ h, const float* __restrict__ intf,
             const unsigned short* __restrict__ sp,
             const float* __restrict__ g_pfs, const float* __restrict__ b_pfs,
             const float* __restrict__ g_sfs, const float* __restrict__ b_sfs,
             float* __restrict__ part_p, float* __restrict__ part_s, int g0)
{
  __shared__ float sred[8];
  const int bl = blockIdx.x, grp = blockIdx.y, t = threadIdx.x;
  float zacc[20], wacc[16];
  #pragma unroll
  for (int j=0;j<20;++j) zacc[j]=0.f;
  #pragma unroll
  for (int j=0;j<16;++j) wacc[j]=0.f;
  for (int rr=0; rr<32; ++rr){
    const size_t r = (size_t)bl*256 + grp*32 + rr;
    float hv[4], iv[16], sv[16];
    #pragma unroll
    for (int j=0;j<4;++j) hv[j] = h[r*1024 + j*256 + t];
    float s1=0.f, s2=0.f;
    #pragma unroll
    for (int j=0;j<16;++j){ float x = intf[r*4096 + j*256 + t]; iv[j]=x; s1+=x; s2+=x*x; }
    blkred2(s1,s2,sred,t);
    const float m1 = s1*(1.f/4096.f);
    const float rs1 = rsqrtf(fmaxf(s2*(1.f/4096.f) - m1*m1, 0.f) + EPSV);
    float t1=0.f, t2=0.f;
    #pragma unroll
    for (int j=0;j<4;++j){ t1 += hv[j]; t2 += hv[j]*hv[j]; }
    #pragma unroll
    for (int j=0;j<16;++j){ float y = (iv[j]-m1)*rs1; iv[j]=y; t1+=y; t2+=y*y; }
    blkred2(t1,t2,sred,t);
    const float m2 = t1*(1.f/5120.f);
    const float rs2 = rsqrtf(fmaxf(t2*(1.f/5120.f) - m2*m2, 0.f) + EPSV);
    #pragma unroll
    for (int j=0;j<4;++j){ int idx = j*256+t; zacc[j] += ((hv[j]-m2)*rs2)*g_pfs[idx] + b_pfs[idx]; }
    #pragma unroll
    for (int j=0;j<16;++j){ int idx = 1024 + j*256+t; zacc[4+j] += ((iv[j]-m2)*rs2)*g_pfs[idx] + b_pfs[idx]; }
    float u1=0.f, u2=0.f;
    #pragma unroll
    for (int j=0;j<16;++j){ float x = bf2f(sp[r*4096 + j*256 + t]); sv[j]=x; u1+=x; u2+=x*x; }
    blkred2(u1,u2,sred,t);
    const float m3 = u1*(1.f/4096.f);
    const float rs3 = rsqrtf(fmaxf(u2*(1.f/4096.f) - m3*m3, 0.f) + EPSV);
    #pragma unroll
    for (int j=0;j<16;++j){ int idx = j*256+t; wacc[j] += ((sv[j]-m3)*rs3)*g_sfs[idx] + b_sfs[idx]; }
  }
  const size_t pb = (size_t)(g0 + bl)*8 + grp;
  #pragma unroll
  for (int j=0;j<20;++j) part_p[pb*5120 + j*256 + t] = zacc[j];
  #pragma unroll
  for (int j=0;j<16;++j) part_s[pb*4096 + j*256 + t] = wacc[j];
}

__global__ __launch_bounds__(256)
void k_reduce(const float* __restrict__ part_p, const float* __restrict__ part_s,
              float* __restrict__ xbar, float* __restrict__ ybar){
  int id = blockIdx.x*256 + threadIdx.x;
  if (id < 32*5120){
    const int b = id / 5120, i = id % 5120;
    float s = 0.f;
    for (int g=0; g<8; ++g) s += part_p[((size_t)b*8+g)*5120 + i];
    xbar[(size_t)b*5120 + i] = s * (1.f/256.f);
  } else {
    id -= 32*5120;
    const int b = id / 4096, i = id % 4096;
    float s = 0.f;
    for (int g=0; g<8; ++g) s += part_s[((size_t)b*8+g)*4096 + i];
    ybar[(size_t)b*4096 + i] = s * (1.f/256.f);
  }
}

__global__ __launch_bounds__(256)
void k_proj_part(const float* __restrict__ xbar, const float* __restrict__ ybar,
                 const float* __restrict__ Wpfs, const float* __restrict__ Wsfs,
                 float* __restrict__ pbuf){
  const int path = blockIdx.z;
  const int y = blockIdx.y;
  if (path == 1 && y >= 8) return;
  const int Kp = path ? 4096 : 5120;
  const float* X = path ? ybar : xbar;
  const float* W = path ? Wsfs : Wpfs;
  const int t = threadIdx.x;
  const int col = blockIdx.x*64 + (t & 63);
  const int sub = t >> 6;
  const int k0 = y*512 + sub*128;
  float acc[32];
  #pragma unroll
  for (int b=0;b<32;++b) acc[b] = 0.f;
  for (int i4=0; i4<32; ++i4){
    const int k = k0 + i4*4;
    float wv0 = W[(size_t)(k  )*1024 + col];
    float wv1 = W[(size_t)(k+1)*1024 + col];
    float wv2 = W[(size_t)(k+2)*1024 + col];
    float wv3 = W[(size_t)(k+3)*1024 + col];
    #pragma unroll
    for (int b=0;b<32;++b){
      float4 xv = *(const float4*)(X + (size_t)b*Kp + k);
      acc[b] += xv.x*wv0 + xv.y*wv1 + xv.z*wv2 + xv.w*wv3;
    }
  }
  float* dst = pbuf + ((size_t)(path*40 + y*4 + sub)*32)*1024 + col;
  #pragma unroll
  for (int b=0;b<32;++b) dst[(size_t)b*1024] = acc[b];
}

__global__ __launch_bounds__(256)
void k_projred(const float* __restrict__ pbuf,
               const float* __restrict__ bpfs, const float* __restrict__ bsfs,
               float* __restrict__ tpre, float* __restrict__ spre){
  const int id = blockIdx.x*256 + threadIdx.x;
  const int path = id >> 15;
  const int rem = id & 32767;
  const int b = rem >> 10, col = rem & 1023;
  const int ns = path ? 32 : 40;
  const float* src = pbuf + ((size_t)(path*40)*32 + b)*1024 + col;
  float s = path ? bsfs[col] : bpfs[col];
  for (int g=0; g<ns; ++g) s += src[(size_t)g*32*1024];
  (path ? spre : tpre)[(size_t)b*1024 + col] = s;
}

__global__ __launch_bounds__(256)
void k_lnrow(const float* __restrict__ tpre, const float* __restrict__ spre,
             float* __restrict__ out){
  __shared__ float sred[8];
  const int id = blockIdx.x, t = threadIdx.x;
  const int path = id >> 5, b = id & 31;
  const float* src = (path ? spre : tpre) + (size_t)b*1024;
  float v[4]; float s1=0.f, s2=0.f;
  #pragma unroll
  for (int j=0;j<4;++j){ v[j] = src[j*256+t]; s1 += v[j]; s2 += v[j]*v[j]; }
  blkred2(s1,s2,sred,t);
  const float m = s1*(1.f/1024.f);
  const float rs = rsqrtf(fmaxf(s2*(1.f/1024.f)-m*m,0.f)+EPSV);
  float* dst = out + (path ? 35072 : 2304) + (size_t)b*1024;
  #pragma unroll
  for (int j=0;j<4;++j) dst[j*256+t] = (v[j]-m)*rs;
}

__global__ __launch_bounds__(256)
void k_head(const float* __restrict__ Wpc, const float* __restrict__ bpc,
            const float* __restrict__ Wc0, const float* __restrict__ bc0,
            const float* __restrict__ Wc1, const float* __restrict__ bc1,
            const float* __restrict__ Wc2, const float* __restrict__ bc2,
            float* __restrict__ out){
  __shared__ float slog[16];
  __shared__ int sy;
  const int b = blockIdx.x, t = threadIdx.x, w = t>>6, l = t&63;
  const float* pv = out + 2304 + (size_t)b*1024;
  const float* sv = out + 35072 + (size_t)b*1024;
  #pragma unroll
  for (int jj=0; jj<4; ++jj){
    const int j = w*4 + jj;
    float a = 0.f;
    for (int i=l; i<1024; i+=64) a += pv[i]*Wpc[(size_t)i*16 + j];
    #pragma unroll
    for (int off=32; off; off>>=1) a += __shfl_xor(a, off);
    if (l==0){ const float lgv = a + bpc[j]; slog[j] = lgv; out[b*16 + j] = lgv; }
  }
  __syncthreads();
  if (t==0){
    int best=0; float bvv = slog[0];
    for (int i=1;i<16;++i) if (slog[i] > bvv){ bvv = slog[i]; best = i; }
    sy = best;
  }
  __syncthreads();
  const int y = sy;
  const float* Ws[3] = {Wc0, Wc1, Wc2};
  const float* bs[3] = {bc0, bc1, bc2};
  const int nouts[3] = {8,16,32};
  const int ooff[3]  = {512, 768, 1280};
  for (int hI=0; hI<3; ++hI){
    const int no = nouts[hI];
    for (int n = w; n < no; n += 4){
      const float* wr = Ws[hI] + ((size_t)y*no + n)*1024;
      float a = 0.f;
      for (int i=l; i<1024; i+=64) a += sv[i]*wr[i];
      #pragma unroll
      for (int off=32; off; off>>=1) a += __shfl_xor(a, off);
      if (l==0) out[ooff[hI] + b*no + n] = a + bs[hI][(size_t)y*no + n];
    }
  }
}

// ---------------------------------------------------------------------------
extern "C" void kernel_launch(void* const* d_in, const int* in_sizes, int n_in,
                              void* d_out, int out_size, void* d_ws, size_t ws_size,
                              hipStream_t stream)
{
  const float* h    = (const float*)d_in[0];
  const float* Wpp  = (const float*)d_in[1];
  const float* bpp  = (const float*)d_in[2];
  const float* Wsp  = (const float*)d_in[3];
  const float* bsp  = (const float*)d_in[4];
  const float* Wq   = (const float*)d_in[5];
  const float* bq   = (const float*)d_in[6];
  const float* Wk   = (const float*)d_in[7];
  const float* bk   = (const float*)d_in[8];
  const float* Wv   = (const float*)d_in[9];
  const float* bv   = (const float*)d_in[10];
  const float* g_pfs= (const float*)d_in[11];
  const float* b_pfs= (const float*)d_in[12];
  const float* Wpfs = (const float*)d_in[13];
  const float* bpfs = (const float*)d_in[14];
  const float* g_sfs= (const float*)d_in[15];
  const float* b_sfs= (const float*)d_in[16];
  const float* Wsfs = (const float*)d_in[17];
  const float* bsfs = (const float*)d_in[18];
  const float* Wpc  = (const float*)d_in[19];
  const float* bpc  = (const float*)d_in[20];
  const float* Wc0  = (const float*)d_in[21];
  const float* bc0  = (const float*)d_in[22];
  const float* Wc1  = (const float*)d_in[23];
  const float* bc1  = (const float*)d_in[24];
  const float* Wc2  = (const float*)d_in[25];
  const float* bc2  = (const float*)d_in[26];
  float* out = (float*)d_out;
  char* ws = (char*)d_ws;
  (void)in_sizes; (void)n_in; (void)out_size;

  // ---- adaptive plan selection (host arithmetic only) ----
  struct PlanT { int G, NS, hoist; };
  const PlanT plans[11] = {
    {32,4096,1},{32,4096,0},{16,4096,1},{16,4096,0},{8,4096,1},{8,4096,0},
    {4,4096,0},{2,4096,0},{1,4096,0},{1,2048,0},{1,1024,0}};
  int G = 0, NS = 0, HOIST = 0;
  size_t oWt=0,oWps=0,oWq=0,oWkv=0;
  size_t oPp=0,oPs=0,oXb=0,oYb=0,oTp=0,oSp=0,oPbf=0,oHb=0,oPb=0,oSb=0,oQ=0,oK=0,oVt=0,oS=0,oP=0;
  for (int pi = 0; pi < 11; ++pi){
    const size_t g = plans[pi].G, ns = plans[pi].NS;
    const int hoist = plans[pi].hoist;
    size_t off = 0;
    auto alloc = [&](size_t bytes){ size_t o = off; off += (bytes + 255) & ~255ULL; return o; };
    size_t wt=0, wps=0, wq=0, wkv=0;
    if (hoist){
      wps = alloc(8192ULL*1024*2);          // [Wpp^T ; Wsp^T]  16 MiB
      wq  = alloc(4096ULL*4096*2);          // Wq^T             32 MiB
      wkv = alloc(8192ULL*4096*2);          // [Wk^T ; Wv^T]    64 MiB
    } else {
      wt = alloc(ns*4096*2);
    }
    size_t pp_ = alloc(32*8*5120*4);
    size_t ps_ = alloc(32*8*4096*4);
    size_t xb = alloc(32*5120*4);
    size_t yb = alloc(32*4096*4);
    size_t tp = alloc(32*1024*4);
    size_t sp_ = alloc(32*1024*4);
    size_t pbf = alloc(2*40*32*1024*4);
    size_t hb = alloc(g*524288);
    size_t pb = alloc(g*2097152);
    size_t sb = alloc(g*2097152);
    size_t q  = alloc(g*2097152);
    size_t k  = alloc(g*2097152);
    size_t vt = alloc(g*2097152);
    size_t s  = alloc(g*1048576);
    size_t p  = alloc(g*524288);
    if (off <= ws_size){
      G = (int)g; NS = (int)ns; HOIST = hoist;
      oWt=wt; oWps=wps; oWq=wq; oWkv=wkv;
      oPp=pp_; oPs=ps_; oXb=xb; oYb=yb; oTp=tp; oSp=sp_; oPbf=pbf;
      oHb=hb; oPb=pb; oSb=sb; oQ=q; oK=k; oVt=vt; oS=s; oP=p;
      break;
    }
  }
  if (!G) return;

  unsigned short* Wt   = (unsigned short*)(ws + oWt);
  unsigned short* WpsT = (unsigned short*)(ws + oWps);
  unsigned short* WqT  = (unsigned short*)(ws + oWq);
  unsigned short* WkvT = (unsigned short*)(ws + oWkv);
  float* part_p = (float*)(ws + oPp);
  float* part_s = (float*)(ws + oPs);
  float* xbar   = (float*)(ws + oXb);
  float* ybar   = (float*)(ws + oYb);
  float* tpre   = (float*)(ws + oTp);
  float* spre   = (float*)(ws + oSp);
  float* pbuf   = (float*)(ws + oPbf);
  unsigned short* h_bf = (unsigned short*)(ws + oHb);
  unsigned short* pp   = (unsigned short*)(ws + oPb);
  unsigned short* sp   = (unsigned short*)(ws + oSb);
  unsigned short* Q    = (unsigned short*)(ws + oQ);
  unsigned short* Kb   = (unsigned short*)(ws + oK);
  unsigned short* Vt   = (unsigned short*)(ws + oVt);
  float*          S    = (float*)(ws + oS);
  unsigned short* P    = (unsigned short*)(ws + oP);
  float*          intf = (float*)(ws + oQ);   // aliases Q+K (contiguous, both dead)

  const float scale = 1.0f/32.0f;
  (void)oK;

  if (HOIST){
    hipLaunchKernelGGL(k_tconv, dim3(64,16), dim3(256), 0, stream, Wpp, WpsT, 1024, 4096);
    hipLaunchKernelGGL(k_tconv, dim3(64,16), dim3(256), 0, stream, Wsp, WpsT + 4096ULL*1024, 1024, 4096);
    hipLaunchKernelGGL(k_tconv, dim3(64,64), dim3(256), 0, stream, Wq, WqT, 4096, 4096);
    hipLaunchKernelGGL(k_tconv, dim3(64,64), dim3(256), 0, stream, Wk, WkvT, 4096, 4096);
    hipLaunchKernelGGL(k_tconv, dim3(64,64), dim3(256), 0, stream, Wv, WkvT + 4096ULL*4096, 4096, 4096);
  }

  for (int g0 = 0; g0 < 32; g0 += G){
    const float* h_g = h + (size_t)g0*262144;

    hipLaunchKernelGGL(k_convh, dim3(G*256), dim3(256), 0, stream, h_g, h_bf);

    if (HOIST){
      // pp,sp = gelu(h @ [Wpp;Wsp] + [bpp;bsp])  (one dispatch, N=8192)
      hipLaunchKernelGGL(gemm256<0>, dim3(32,G), dim3(512), 0, stream,
                         h_bf, WpsT, bpp, bsp, (void*)pp, (void*)sp, 1024, 1024,1024,4096);
      // Q = pp @ Wq + bq
      hipLaunchKernelGGL(gemm256<1>, dim3(16,G), dim3(512), 0, stream,
                         pp, WqT, bq, bq, (void*)Q, (void*)Q, 4096, 4096,4096,4096);
      // K,Vt = sp @ [Wk;Wv] + [bk;bv]  (one dispatch; V written transposed)
      hipLaunchKernelGGL(gemm256<4>, dim3(32,G), dim3(512), 0, stream,
                         sp, WkvT, bk, bv, (void*)Kb, (void*)Vt, 4096, 4096,4096,4096);
    } else {
      hipLaunchKernelGGL(k_tconv, dim3(64,16), dim3(256), 0, stream, Wpp, Wt, 1024, 4096);
      hipLaunchKernelGGL(gemm256<0>, dim3(16,G), dim3(512), 0, stream,
                         h_bf, Wt, bpp, bpp, (void*)pp, (void*)pp, 1024, 1024,1024,4096);
      for (int nso = 0; nso < 4096; nso += NS){
        hipLaunchKernelGGL(k_tconv, dim3(NS/64,64), dim3(256), 0, stream, Wq + nso, Wt, 4096, 4096);
        hipLaunchKernelGGL(gemm256<1>, dim3(NS/256,G), dim3(512), 0, stream,
                           pp, Wt, bq + nso, bq + nso, (void*)(Q + nso), (void*)(Q + nso), 4096, 4096,4096,4096);
      }
      hipLaunchKernelGGL(k_tconv, dim3(64,16), dim3(256), 0, stream, Wsp, Wt, 1024, 4096);
      hipLaunchKernelGGL(gemm256<0>, dim3(16,G), dim3(512), 0, stream,
                         h_bf, Wt, bsp, bsp, (void*)sp, (void*)sp, 1024, 1024,1024,4096);
      for (int nso = 0; nso < 4096; nso += NS){
        hipLaunchKernelGGL(k_tconv, dim3(NS/64,64), dim3(256), 0, stream, Wk + nso, Wt, 4096, 4096);
        hipLaunchKernelGGL(gemm256<1>, dim3(NS/256,G), dim3(512), 0, stream,
                           sp, Wt, bk + nso, bk + nso, (void*)(Kb + nso), (void*)(Kb + nso), 4096, 4096,4096,4096);
      }
      for (int nso = 0; nso < 4096; nso += NS){
        hipLaunchKernelGGL(k_tconv, dim3(NS/64,64), dim3(256), 0, stream, Wv + nso, Wt, 4096, 4096);
        hipLaunchKernelGGL(gemm256<3>, dim3(NS/256,G), dim3(512), 0, stream,
                           sp, Wt, bv + nso, bv + nso, (void*)(Vt + (size_t)nso*256), (void*)(Vt + (size_t)nso*256), 4096, 4096,4096,256);
      }
    }
    // S = scale * Q K^T  (batched z = b_local*4 + h)
    hipLaunchKernelGGL(gemm_bt<2>, dim3(2,2,G*4), dim3(256), 0, stream,
                       Q, Kb, (const float*)nullptr, (void*)S, 1024, 4096,4096,256,
                       1048576L,1024L, 1048576L,1024L, 262144L,65536L, scale);
    hipLaunchKernelGGL(k_softmax, dim3(G*256), dim3(256), 0, stream, S, P);
    // intf = P V  (fp32 out; overwrites Q+K region)
    hipLaunchKernelGGL(gemm_bt<2>, dim3(8,2,G*4), dim3(256), 0, stream,
                       P, Vt, (const float*)nullptr, (void*)intf, 256, 256,256,4096,
                       262144L,65536L, 1048576L,262144L, 1048576L,1024L, 1.f);
    // fused LN-stat partial means
    hipLaunchKernelGGL(k_stats, dim3(G,8), dim3(256), 0, stream,
                       h_g, intf, sp, g_pfs, b_pfs, g_sfs, b_sfs, part_p, part_s, g0);
  }

  hipLaunchKernelGGL(k_reduce, dim3(1152), dim3(256), 0, stream, part_p, part_s, xbar, ybar);
  hipLaunchKernelGGL(k_proj_part, dim3(16,10,2), dim3(256), 0, stream,
                     xbar, ybar, Wpfs, Wsfs, pbuf);
  hipLaunchKernelGGL(k_projred, dim3(256), dim3(256), 0, stream,
                     pbuf, bpfs, bsfs, tpre, spre);
  hipLaunchKernelGGL(k_lnrow, dim3(64), dim3(256), 0, stream, tpre, spre, out);
  hipLaunchKernelGGL(k_head, dim3(32), dim3(256), 0, stream,
                     Wpc, bpc, Wc0, bc0, Wc1, bc1, Wc2, bc2, out);
}